// Round 6
// baseline (193.035 us; speedup 1.0000x reference)
//
#include <hip/hip_runtime.h>

#define TDIM 128
#define KP 40   // K stride in bf16 elems: 80 B rows -> every 16B chunk aligned

typedef __attribute__((ext_vector_type(8))) short short8;
typedef __attribute__((ext_vector_type(4))) float float4v;

__host__ __device__ inline int trivalid(int l, int l1, int l2) {
  int d = l1 - l2; if (d < 0) d = -d;
  return (l >= d && l <= l1 + l2) ? 1 : 0;
}

__device__ __forceinline__ float u2f(unsigned int u) {
  union { unsigned int u; float f; } w; w.u = u; return w.f;
}
__device__ __forceinline__ float bf2f(unsigned short v) {
  return u2f(((unsigned int)v) << 16);
}
__device__ __forceinline__ unsigned short f2bf(float x) {
  union { float f; unsigned int u; } w; w.f = x;
  unsigned int u = w.u;
  u += 0x7fffu + ((u >> 16) & 1u);   // round-to-nearest-even
  return (unsigned short)(u >> 16);
}

// One block per output row r (2416). out[r*16384 + t1*128 + t2] =
//   sum_k coef[k] * clms[i0+k][t1] * clms[j0-k][t2]   (k = 0..nnz-1, nnz<=15)
// == (128x128) = A^T(K x 128, coef-folded) * B(K x 128), K padded to 32 ->
// one v_mfma_f32_16x16x32_bf16 per 16x16 output tile (16 tiles/wave).
__global__ __launch_bounds__(256)
void cg_kernel(const void* __restrict__ clms_raw,
               const void* __restrict__ C_raw,
               void* __restrict__ out_raw) {
  __shared__ unsigned short sa[TDIM * KP];  // sa[m][k] = bf16(coef[k]*clms[i0+k][m]), k>=nnz -> 0
  __shared__ unsigned short sb[TDIM * KP];  // sb[n][k] = bf16(clms[j0-k][n]),        k>=nnz -> 0
  __shared__ float scoef[32];

  const int tid = threadIdx.x;

  // ---- dtype sniff (uniform; proven in rounds 3/5) ----
  const unsigned int* cw = (const unsigned int*)clms_raw;
  int cnt_bf = 0;
  #pragma unroll
  for (int i = 0; i < 32; ++i) {
    unsigned int e = (cw[i] >> 7) & 0xFFu;
    cnt_bf += (e >= 110u && e <= 135u) ? 1 : 0;
  }
  const bool in_bf16 = (cnt_bf >= 16);
  const bool c_bf16 = ((*(const unsigned int*)C_raw) & 0xffffu) == 0x3f80u;

  // ---- decode blockIdx -> (l, m, l1, l2); uniform (proven) ----
  const int r = blockIdx.x;
  int rem = r, l = 0, cnt = 0;
  for (l = 0; l < 8; ++l) {
    cnt = 0;
    for (int a = 0; a < 8; ++a)
      for (int b = 0; b < 8; ++b) cnt += trivalid(l, a, b);
    int rows = (2 * l + 1) * cnt;
    if (rem < rows) break;
    rem -= rows;
  }
  const int mi = rem / cnt;
  const int p  = rem - mi * cnt;
  const int m  = mi - l;
  int l1 = 0, l2 = 0;
  {
    int q = 0; bool done = false;
    for (int a = 0; a < 8 && !done; ++a)
      for (int b = 0; b < 8; ++b) {
        if (trivalid(l, a, b)) {
          if (q == p) { l1 = a; l2 = b; done = true; break; }
          ++q;
        }
      }
  }

  const int m1lo = (-l1 > m - l2) ? -l1 : (m - l2);
  const int m1hi = ( l1 < m + l2) ?  l1 : (m + l2);
  const int nnz = m1hi - m1lo + 1;            // 1..15
  const int i0 = l1 * (l1 + 1) + m1lo;        // A rows: i0+k (valid for k<nnz)
  const int j0 = l2 * (l2 + 1) + m - m1lo;    // B rows: j0-k

  // ---- coefficients, zero-padded to 32 (K of the MFMA) ----
  if (tid < 32) {
    float v = 0.0f;
    if (tid < nnz) {
      int m1 = m1lo + tid, m2 = m - m1;
      int i = l1 * (l1 + 1) + m1;
      int j = l2 * (l2 + 1) + m2;
      int k = l  * (l  + 1) + m;
      int ci = (k * 64 + i) * 64 + j;
      v = c_bf16 ? bf2f(((const unsigned short*)C_raw)[ci])
                 : ((const float*)C_raw)[ci];
    }
    scoef[tid] = v;
  }
  __syncthreads();

  if (in_bf16) {
    // ---- stage sa/sb transposed (K contiguous), 512 chunks of 8 bf16 each ----
    const unsigned short* cl = (const unsigned short*)clms_raw;
    #pragma unroll
    for (int c0 = 0; c0 < 2; ++c0) {
      int c  = tid + c0 * 256;   // 0..511
      int t  = c >> 2;           // 0..127
      int kc = c & 3;            // chunk of 8 along K
      union { unsigned short u[8]; uint4 v; } pa, pb;
      #pragma unroll
      for (int j = 0; j < 8; ++j) {
        int k  = kc * 8 + j;
        int qa = (k < nnz) ? k : 0;                     // clamp: stays in-range
        unsigned short araw = cl[(i0 + qa) * TDIM + t];
        unsigned short braw = cl[(j0 - qa) * TDIM + t];
        pa.u[j] = (k < nnz) ? f2bf(scoef[k] * bf2f(araw)) : (unsigned short)0;
        pb.u[j] = (k < nnz) ? braw : (unsigned short)0;
      }
      *(uint4*)&sa[t * KP + kc * 8] = pa.v;   // (t*40+kc*8)*2 = t*80+kc*16: 16B aligned
      *(uint4*)&sb[t * KP + kc * 8] = pb.v;
    }
    __syncthreads();

    // ---- MFMA: wave w -> m-tiles {2w,2w+1} x n-tiles 0..7 ----
    const int lane = tid & 63;
    const int w    = tid >> 6;
    const int col  = lane & 15;
    const int quad = lane >> 4;
    unsigned short* outp = (unsigned short*)out_raw;
    const unsigned long long outbase = (unsigned long long)r * (TDIM * TDIM);

    // A-frag: A[m=lane&15][k=quad*8+j]  (m120-verified layout)
    short8 af0 = *(const short8*)&sa[((2 * w + 0) * 16 + col) * KP + quad * 8];
    short8 af1 = *(const short8*)&sa[((2 * w + 1) * 16 + col) * KP + quad * 8];

    #pragma unroll
    for (int tn = 0; tn < 8; ++tn) {
      // B-frag: B[k=quad*8+j][n=lane&15]
      short8 bf = *(const short8*)&sb[(tn * 16 + col) * KP + quad * 8];
      float4v acc0 = {0.f, 0.f, 0.f, 0.f};
      float4v acc1 = {0.f, 0.f, 0.f, 0.f};
      acc0 = __builtin_amdgcn_mfma_f32_16x16x32_bf16(af0, bf, acc0, 0, 0, 0);
      acc1 = __builtin_amdgcn_mfma_f32_16x16x32_bf16(af1, bf, acc1, 0, 0, 0);
      // C/D: col=lane&15, row=quad*4+reg (m89/m91-verified)
      #pragma unroll
      for (int rg = 0; rg < 4; ++rg) {
        int t1a = (2 * w + 0) * 16 + quad * 4 + rg;
        int t1b = (2 * w + 1) * 16 + quad * 4 + rg;
        outp[outbase + (unsigned long long)(t1a * TDIM + tn * 16 + col)] = f2bf(acc0[rg]);
        outp[outbase + (unsigned long long)(t1b * TDIM + tn * 16 + col)] = f2bf(acc1[rg]);
      }
    }
  } else {
    // ---- f32 fallback: correct, straightforward (not expected to execute) ----
    __syncthreads();
    const float* clf = (const float*)clms_raw;
    float* outp = (float*)out_raw;
    const int tx = tid & 31;
    const int ty = tid >> 5;
    const int t2 = tx * 4;
    const unsigned long long outbase = (unsigned long long)r * (TDIM * TDIM);
    for (int s = 0; s < 16; ++s) {
      int t1 = ty + 8 * s;
      float ax = 0.f, ay = 0.f, az = 0.f, aw = 0.f;
      for (int q = 0; q < nnz; ++q) {          // nnz uniform -> scalar loop
        float ca = scoef[q] * clf[(i0 + q) * TDIM + t1];
        const float* bp = &clf[(j0 - q) * TDIM + t2];
        ax += ca * bp[0]; ay += ca * bp[1]; az += ca * bp[2]; aw += ca * bp[3];
      }
      float4 o; o.x = ax; o.y = ay; o.z = az; o.w = aw;
      *(float4*)(outp + outbase + (unsigned long long)(t1 * TDIM + t2)) = o;
    }
  }
}

extern "C" void kernel_launch(void* const* d_in, const int* in_sizes, int n_in,
                              void* d_out, int out_size, void* d_ws, size_t ws_size,
                              hipStream_t stream) {
  (void)in_sizes; (void)n_in; (void)d_ws; (void)ws_size;
  const int nrows = out_size / (TDIM * TDIM);   // 2416 for L=7, T=128
  cg_kernel<<<nrows, 256, 0, stream>>>(d_in[0], d_in[1], d_out);
}